// Round 15
// baseline (492.721 us; speedup 1.0000x reference)
//
#include <hip/hip_runtime.h>
#include <hip/hip_bf16.h>
#include <cstdint>

typedef __attribute__((ext_vector_type(8))) __bf16 bf16x8;
typedef __attribute__((ext_vector_type(4))) __bf16 bf16x4;
typedef __attribute__((ext_vector_type(4))) float  f32x4;

#define N_IMG 3136   // 56*56
#define NB16  196    // 3136/16
#define CB8   56     // 448/8
#define P_CNT 2496   // 52*48 interior pixels
#define NDIR  34     // stencil directions

// stencil offsets dy*56+dx for RADIUS=5 (matches get_indices_of_pairs order)
__constant__ int c_offs[NDIR] = {
  1,2,3,4,
  52,53,54,55,56,57,58,59,60,
  108,109,110,111,112,113,114,115,116,
  165,166,167,168,169,170,171,
  222,223,224,225,226};

__device__ __forceinline__ void block_sync(){
  asm volatile("s_waitcnt lgkmcnt(0)");   // LDS retired (no memory clobber)
  __builtin_amdgcn_s_barrier();
}

__device__ __forceinline__ float elu_f(float v){
  return v > 0.f ? v : expm1f(v);
}

// ---------------- weight f32->bf16 prep (one launch, 4 segments) -------------
__global__ __launch_bounds__(256) void cvt_weights(
    const float* __restrict__ w83, const float* __restrict__ w84,
    const float* __restrict__ w85, const float* __restrict__ w9,
    __bf16* __restrict__ o83, __bf16* __restrict__ o84,
    __bf16* __restrict__ o85, __bf16* __restrict__ o9)
{
  int i = blockIdx.x*256 + threadIdx.x;  // index in float4 units
  const float* src; __bf16* dst; int off;
  if      (i <   8192){ src=w83; dst=o83; off=i; }
  else if (i <  40960){ src=w84; dst=o84; off=i-8192; }
  else if (i < 303104){ src=w85; dst=o85; off=i-40960; }
  else if (i < 353280){ src=w9 ; dst=o9 ; off=i-303104; }
  else return;
  f32x4 v = ((const f32x4*)src)[off];
  bf16x4 o;
  o[0]=(__bf16)v[0]; o[1]=(__bf16)v[1]; o[2]=(__bf16)v[2]; o[3]=(__bf16)v[3];
  ((bf16x4*)dst)[off] = o;
}

// ---------------- xcvt: f32 n-major -> bf16 granule tiles ---------------------
// Output tile(pair, kb) is CONTIGUOUS 8KB: elem (k,n) at n*64 + (k>>3)*8 + (k&7)
// (k,n local to the 64x64 tile; pair = b*49+nt).  Tiles of one pair are
// consecutive over kb -> each GEMM block streams a contiguous 64*8KB run.
// Per block: one (b,kb,nc) with 7 tiles (n-chunk of 448).  Transpose via
// 32-row half-tiles in pad-65 f32 LDS: both LDS sides verified 2-way banks.
template<int KTOT>
__device__ __forceinline__ void xcvt_body(
    const float* __restrict__ X, __bf16* __restrict__ Xt,
    int b, int kb, int nc, float* T /* [32][65] */)
{
  constexpr int NSLAB = KTOT/64;
  const int tid = threadIdx.x;
  const int r  = tid >> 3, o  = tid & 7;   // staging: row 0..31, octet 0..7
  const int n_ = tid >> 2, g_ = tid & 3;   // emit: n 0..63, local granule 0..3

  for (int t = 0; t < 7; ++t){
    const int nt = nc*7 + t;
    const float* src = X + ((size_t)b*KTOT + kb*64)*N_IMG + nt*64;
    __bf16* dst = Xt + (((size_t)(b*49 + nt))*NSLAB + kb)*4096;
    #pragma unroll
    for (int half = 0; half < 2; ++half){
      // stage 32 rows x 64 cols f32 (coalesced 32B/thread)
      const float* rp = src + (size_t)(half*32 + r)*N_IMG + o*8;
      f32x4 v0 = *(const f32x4*)(rp);
      f32x4 v1 = *(const f32x4*)(rp + 4);
      float* Tr = &T[r*65 + o*8];
      #pragma unroll
      for (int e=0;e<4;++e){ Tr[e] = v0[e]; Tr[4+e] = v1[e]; }
      block_sync();
      // emit: granule (n, half*4+g): 8 column reads (2-way banks), 1 16B store
      bf16x8 w;
      #pragma unroll
      for (int j=0;j<8;++j) w[j] = (__bf16)T[(g_*8 + j)*65 + n_];
      *(bf16x8*)(dst + n_*64 + (half*4 + g_)*8) = w;
      block_sync();   // T reused next half
    }
  }
}

__global__ __launch_bounds__(256, 4) void xcvt(
    const float* __restrict__ c4, const float* __restrict__ c5,
    const float* __restrict__ c6,
    __bf16* __restrict__ xt4, __bf16* __restrict__ xt5, __bf16* __restrict__ xt6)
{
  __shared__ float T[32*65];
  const int gid = blockIdx.x;
  if (gid < 1792){           // conv6: 4b x 64kb x 7nc
    const int b = gid/448, rem = gid%448;
    xcvt_body<4096>(c6, xt6, b, rem/7, rem%7, T);
  } else if (gid < 2240){    // conv5: 4b x 16kb x 7nc
    const int g = gid-1792, b = g/112, rem = g%112;
    xcvt_body<1024>(c5, xt5, b, rem/7, rem%7, T);
  } else {                   // conv4: 4b x 8kb x 7nc
    const int g = gid-2240, b = g/56, rem = g%56;
    xcvt_body<512>(c4, xt4, b, rem/7, rem%7, T);
  }
}

// ---------------- fused feature GEMMs: ZERO LDS, ZERO barriers ----------------
// y1[n,c] = elu(W * X).  B frag-loaded straight from contiguous granule tiles
// (each frag-load inst covers 16 full 64B lines; 4 waves/block share the 8KB
// tile through L1).  A frag-loaded from L2.  Pure load->MFMA stream — the
// structure gemm_out already proved; compiler pipelines with counted vmcnt.
// XCD co-location mapping kept from R12 (FETCH 476->170MB win).
// Output in MFMA-B-fragment layout: idx=(((b*196+n/16)*56+c/8)*16+n%16)*8+c%8
template<int NSLAB>
__device__ __forceinline__ void feat_body(
    const __bf16* __restrict__ Xtp,    // Xt + pair*NSLAB*4096
    const __bf16* __restrict__ Wrow,   // W + m0*KTOT
    __bf16* __restrict__ y1, int c_base, int b, int n0)
{
  constexpr int KTOT = NSLAB*64;
  const int lane = threadIdx.x & 63;
  const int wm   = threadIdx.x >> 6;   // 0..3
  const int l15  = lane & 15;
  const int l4   = lane >> 4;

  const __bf16* tb0 = Xtp + l15*64 + l4*8;                    // + s*4096 + ni*1024 (+32 for kk=1)
  const __bf16* ta0 = Wrow + (size_t)(wm*16 + l15)*KTOT + l4*8;  // + s*64 (+32)

  f32x4 acc[4];
  const f32x4 fz = {0.f,0.f,0.f,0.f};
  #pragma unroll
  for (int ni=0; ni<4; ++ni) acc[ni] = fz;

  #pragma unroll 4
  for (int s=0; s<NSLAB; ++s){
    const __bf16* tb = tb0 + (size_t)s*4096;
    const __bf16* ta = ta0 + s*64;
    bf16x8 a0 = *(const bf16x8*)(ta);
    bf16x8 a1 = *(const bf16x8*)(ta + 32);
    #pragma unroll
    for (int ni=0; ni<4; ++ni){
      bf16x8 bv = *(const bf16x8*)(tb + ni*1024);
      acc[ni] = __builtin_amdgcn_mfma_f32_16x16x32_bf16(a0, bv, acc[ni], 0,0,0);
    }
    #pragma unroll
    for (int ni=0; ni<4; ++ni){
      bf16x8 bv = *(const bf16x8*)(tb + ni*1024 + 32);
      acc[ni] = __builtin_amdgcn_mfma_f32_16x16x32_bf16(a1, bv, acc[ni], 0,0,0);
    }
  }

  // ---- epilogue: elu + store to fragment layout ----
  const int c0 = c_base + wm*16 + l4*4;
  const int cb = c0 >> 3;
  const int jj = c0 & 7;
  #pragma unroll
  for (int ni=0; ni<4; ++ni){
    const int n = n0 + ni*16 + l15;
    size_t idx = ((((size_t)b*NB16 + (n>>4))*CB8 + cb)*16 + (n&15))*8 + jj;
    f32x4 a = acc[ni];
    bf16x4 o;
    #pragma unroll
    for (int r=0;r<4;++r) o[r] = (__bf16)elu_f(a[r]);
    *(bf16x4*)(y1 + idx) = o;
  }
}

__global__ __launch_bounds__(256, 8) void gemm_feat_fused(
    const __bf16* __restrict__ xt4, const __bf16* __restrict__ xt5,
    const __bf16* __restrict__ xt6,
    const __bf16* __restrict__ w83b, const __bf16* __restrict__ w84b,
    const __bf16* __restrict__ w85b, __bf16* __restrict__ y1)
{
  const int gid = blockIdx.x;
  if (gid < 800){
    // conv6: 4 mt-blocks of each pair co-located on one XCD (gids = x mod 8)
    const int q = gid >> 5, r = gid & 31, mt = r >> 3, x = r & 7;
    const int pair = q*8 + x;
    if (pair >= 196) return;
    const int b = pair/49, nt = pair%49;
    feat_body<64>(xt6 + (size_t)pair*64*4096, w85b + (size_t)mt*64*4096,
                  y1, 192 + mt*64, b, nt*64);
  } else if (gid < 1200){
    // conv5: 2 mt-blocks of each pair co-located
    const int g = gid-800, q = g >> 4, r = g & 15, mt = r >> 3, x = r & 7;
    const int pair = q*8 + x;
    if (pair >= 196) return;
    const int b = pair/49, nt = pair%49;
    feat_body<16>(xt5 + (size_t)pair*16*4096, w84b + (size_t)mt*64*1024,
                  y1, 64 + mt*64, b, nt*64);
  } else {
    // conv4: no sharing
    const int pair = gid-1200;
    const int b = pair/49, nt = pair%49;
    feat_body<8>(xt4 + (size_t)pair*8*4096, w83b,
                 y1, 0, b, nt*64);
  }
}

// ---------------- output GEMM: x2[n, o] = elu(w9[448x448] * y1) -------------
// LDS-free, barrier-free: both operands frag-loaded direct (L2/L3-resident).
__global__ __launch_bounds__(256) void gemm_out(
    const __bf16* __restrict__ y1, const __bf16* __restrict__ w9b,
    __bf16* __restrict__ x2)
{
  const int nt = blockIdx.x, mt = blockIdx.y, b = blockIdx.z;
  const int tid = threadIdx.x;
  if (mt == 7){
    // zero the pad columns 448..511 of this n-tile
    const int row = tid >> 2, q = tid & 3;
    __bf16* p = x2 + ((size_t)b*N_IMG + nt*64 + row)*512 + 448 + q*16;
    uint4 z = {0u,0u,0u,0u};
    *(uint4*)p = z;
    *(uint4*)(p+8) = z;
    return;
  }
  const int lane = tid & 63, wid = tid >> 6;
  const int l15 = lane & 15, l4 = lane >> 4;
  const __bf16* Bbase = y1 + ((size_t)b*NB16 + nt*4 + wid)*CB8*128;
  const __bf16* Abase = w9b + (size_t)(mt*64 + l15)*448 + l4*8;
  f32x4 acc[4];
  const f32x4 fz = {0.f,0.f,0.f,0.f};
  #pragma unroll
  for (int mi=0;mi<4;++mi) acc[mi] = fz;

  for (int s=0;s<7;++s){
    #pragma unroll
    for (int kk=0;kk<2;++kk){
      bf16x8 bv = *(const bf16x8*)(Bbase + (s*2+kk)*512 + lane*8);  // linear lane*16B
      #pragma unroll
      for (int mi=0;mi<4;++mi){
        bf16x8 av = *(const bf16x8*)(Abase + (size_t)mi*16*448 + s*64 + kk*32);
        acc[mi] = __builtin_amdgcn_mfma_f32_16x16x32_bf16(av, bv, acc[mi], 0,0,0);
      }
    }
  }
  #pragma unroll
  for (int mi=0;mi<4;++mi){
    const int o = mt*64 + mi*16 + l4*4;
    const int n = nt*64 + wid*16 + l15;
    f32x4 a = acc[mi];
    bf16x4 v;
    #pragma unroll
    for (int r=0;r<4;++r) v[r] = (__bf16)elu_f(a[r]);
    *(bf16x4*)(x2 + ((size_t)b*N_IMG + n)*512 + o) = v;
  }
}

// ---------------- affinity stencil: one wave per (b, p) ---------------------
__global__ __launch_bounds__(256) void affinity_kernel(
    const __bf16* __restrict__ x2, float* __restrict__ out)
{
  const int b = blockIdx.x;                 // b fastest -> each XCD sees one batch
  const int lane = threadIdx.x & 63, wid = threadIdx.x >> 6;
  const int p = blockIdx.y*4 + wid;
  const int from = (p/48)*56 + 4 + (p%48);
  const __bf16* xb = x2 + (size_t)b*N_IMG*512;
  bf16x8 ffv = *(const bf16x8*)(xb + (size_t)from*512 + lane*8);
  float ff[8];
  #pragma unroll
  for (int j=0;j<8;++j) ff[j] = (float)ffv[j];
  for (int d=0; d<NDIR; ++d){
    const int to = from + c_offs[d];
    bf16x8 ftv = *(const bf16x8*)(xb + (size_t)to*512 + lane*8);
    float s = 0.f;
    #pragma unroll
    for (int j=0;j<8;++j) s += fabsf(ff[j] - (float)ftv[j]);
    #pragma unroll
    for (int m=1;m<64;m<<=1) s += __shfl_xor(s, m, 64);
    if (lane == 0) out[((size_t)b*NDIR + d)*P_CNT + p] = expf(-s*(1.f/448.f));
  }
}

extern "C" void kernel_launch(void* const* d_in, const int* in_sizes, int n_in,
                              void* d_out, int out_size, void* d_ws, size_t ws_size,
                              hipStream_t stream)
{
  (void)in_sizes; (void)n_in; (void)out_size; (void)ws_size;
  const float* conv4 = (const float*)d_in[0];
  const float* conv5 = (const float*)d_in[1];
  const float* conv6 = (const float*)d_in[2];
  const float* w83   = (const float*)d_in[3];
  const float* w84   = (const float*)d_in[4];
  const float* w85   = (const float*)d_in[5];
  const float* w9    = (const float*)d_in[6];
  // ind_from / ind_to (d_in[7], d_in[8]) are recomputed on device (hardcoded stencil)
  float* out = (float*)d_out;
  char* ws = (char*)d_ws;
  // workspace layout (168,206,336 bytes)
  __bf16* w83b = (__bf16*)(ws + 0);          //  64x512
  __bf16* w84b = (__bf16*)(ws + 65536);      // 128x1024
  __bf16* w85b = (__bf16*)(ws + 327680);     // 256x4096
  __bf16* w9b  = (__bf16*)(ws + 2424832);    // 448x448
  __bf16* y1   = (__bf16*)(ws + 2826240);    // 4*3136*448, fragment layout
  __bf16* x2   = (__bf16*)(ws + 14065664);   // 4*3136*512 (448 + zero pad)
  __bf16* xt6  = (__bf16*)(ws + 26910720);   // 196 pairs x 64 slabs x 8KB
  __bf16* xt5  = (__bf16*)(ws + 129671168);  // 196 x 16 x 8KB
  __bf16* xt4  = (__bf16*)(ws + 155361280);  // 196 x  8 x 8KB

  cvt_weights<<<1380, 256, 0, stream>>>(w83,w84,w85,w9, w83b,w84b,w85b,w9b);
  // [0,1792)=conv6, [1792,2240)=conv5, [2240,2464)=conv4
  xcvt<<<2464, 256, 0, stream>>>(conv4, conv5, conv6, xt4, xt5, xt6);
  // fused, XCD co-located: [0,800)=conv6, [800,1200)=conv5, [1200,1396)=conv4
  gemm_feat_fused<<<1396, 256, 0, stream>>>(xt4, xt5, xt6, w83b, w84b, w85b, y1);
  gemm_out<<<dim3(49,8,4), 256, 0, stream>>>(y1, w9b, x2);
  affinity_kernel<<<dim3(4,624), 256, 0, stream>>>(x2, out);
}

// Round 16
// 250.380 us; speedup vs baseline: 1.9679x; 1.9679x over previous
//
#include <hip/hip_runtime.h>
#include <hip/hip_bf16.h>
#include <cstdint>

typedef __attribute__((ext_vector_type(8))) __bf16 bf16x8;
typedef __attribute__((ext_vector_type(4))) __bf16 bf16x4;
typedef __attribute__((ext_vector_type(4))) float  f32x4;

#define N_IMG 3136   // 56*56
#define NB16  196    // 3136/16
#define CB8   56     // 448/8
#define P_CNT 2496   // 52*48 interior pixels
#define NDIR  34     // stencil directions

// stencil offsets dy*56+dx for RADIUS=5 (matches get_indices_of_pairs order)
__constant__ int c_offs[NDIR] = {
  1,2,3,4,
  52,53,54,55,56,57,58,59,60,
  108,109,110,111,112,113,114,115,116,
  165,166,167,168,169,170,171,
  222,223,224,225,226};

__device__ __forceinline__ void block_sync(){
  asm volatile("s_waitcnt lgkmcnt(0)");   // LDS retired (no memory clobber)
  __builtin_amdgcn_s_barrier();
}

__device__ __forceinline__ float elu_f(float v){
  return v > 0.f ? v : expm1f(v);
}

// async global->LDS, 16B per lane.  LDS dst is WAVE-UNIFORM base (HW adds
// lane*16); global src is PER-LANE.  No VGPR destination => nothing for the
// register allocator to sink (the R5-R15 pathology).  Completion via vmcnt.
__device__ __forceinline__ void gload16(const void* g, void* l){
  __builtin_amdgcn_global_load_lds(
      (const __attribute__((address_space(1))) void*)g,
      (__attribute__((address_space(3))) void*)l, 16, 0, 0);
}

// ---------------- weight f32->bf16 prep (one launch, 4 segments) -------------
__global__ __launch_bounds__(256) void cvt_weights(
    const float* __restrict__ w83, const float* __restrict__ w84,
    const float* __restrict__ w85, const float* __restrict__ w9,
    __bf16* __restrict__ o83, __bf16* __restrict__ o84,
    __bf16* __restrict__ o85, __bf16* __restrict__ o9)
{
  int i = blockIdx.x*256 + threadIdx.x;  // index in float4 units
  const float* src; __bf16* dst; int off;
  if      (i <   8192){ src=w83; dst=o83; off=i; }
  else if (i <  40960){ src=w84; dst=o84; off=i-8192; }
  else if (i < 303104){ src=w85; dst=o85; off=i-40960; }
  else if (i < 353280){ src=w9 ; dst=o9 ; off=i-303104; }
  else return;
  f32x4 v = ((const f32x4*)src)[off];
  bf16x4 o;
  o[0]=(__bf16)v[0]; o[1]=(__bf16)v[1]; o[2]=(__bf16)v[2]; o[3]=(__bf16)v[3];
  ((bf16x4*)dst)[off] = o;
}

// ---------------- xcvt: f32 n-major -> bf16 SWIZZLED granule tiles ------------
// Tile(pair,kb) contiguous 8KB.  Granule gi (k-rows gi*8..+7) of row n stored
// at elem n*64 + ((gi ^ (n&7))<<3)  — the XOR pre-swizzle that makes the GEMM
// ds_read_b128 conflict-free while global_load_lds copies LINEARLY (rule #21).
// Grid split by half-tile (independent granules) for 2x latency parallelism;
// next-tile f32 loads issued before the barrier (2-deep reg pipeline).
template<int KTOT>
__device__ __forceinline__ void xcvt_body(
    const float* __restrict__ X, __bf16* __restrict__ Xt,
    int b, int kb, int nc, int half, float* T /* [32][65] */)
{
  constexpr int NSLAB = KTOT/64;
  const int tid = threadIdx.x;
  const int r  = tid >> 3, o  = tid & 7;   // staging: row 0..31, octet 0..7
  const int n_ = tid >> 2, g_ = tid & 3;   // emit: n 0..63, local granule 0..3
  const float* rp0 = X + ((size_t)b*KTOT + kb*64 + half*32 + r)*N_IMG
                       + nc*448 + o*8;

  f32x4 v0 = *(const f32x4*)(rp0);
  f32x4 v1 = *(const f32x4*)(rp0 + 4);
  for (int t = 0; t < 7; ++t){
    float* Tr = &T[r*65 + o*8];
    #pragma unroll
    for (int e=0;e<4;++e){ Tr[e] = v0[e]; Tr[4+e] = v1[e]; }
    if (t+1 < 7){                          // prefetch next tile's f32 rows
      const float* rp = rp0 + (t+1)*64;
      v0 = *(const f32x4*)(rp);
      v1 = *(const f32x4*)(rp + 4);
    }
    __builtin_amdgcn_sched_barrier(0);
    block_sync();
    bf16x8 w;
    #pragma unroll
    for (int j=0;j<8;++j) w[j] = (__bf16)T[(g_*8 + j)*65 + n_];
    __bf16* dst = Xt + (((size_t)(b*49 + nc*7 + t))*NSLAB + kb)*4096;
    *(bf16x8*)(dst + n_*64 + (((half*4 + g_) ^ (n_ & 7))<<3)) = w;
    block_sync();   // T reused next tile
  }
}

__global__ __launch_bounds__(256) void xcvt(
    const float* __restrict__ c4, const float* __restrict__ c5,
    const float* __restrict__ c6,
    __bf16* __restrict__ xt4, __bf16* __restrict__ xt5, __bf16* __restrict__ xt6)
{
  __shared__ float T[32*65];
  const int gid = blockIdx.x;
  if (gid < 3584){           // conv6: 4b x 64kb x 7nc x 2half
    const int b = gid/896, rem = gid%896;
    xcvt_body<4096>(c6, xt6, b, rem/14, (rem%14)>>1, rem&1, T);
  } else if (gid < 4480){    // conv5: 4b x 16kb x 7nc x 2half
    const int g = gid-3584, b = g/224, rem = g%224;
    xcvt_body<1024>(c5, xt5, b, rem/14, (rem%14)>>1, rem&1, T);
  } else {                   // conv4: 4b x 8kb x 7nc x 2half
    const int g = gid-4480, b = g/112, rem = g%112;
    xcvt_body<512>(c4, xt4, b, rem/14, (rem%14)>>1, rem&1, T);
  }
}

// ---------------- fused feature GEMMs: m97-style global_load_lds loop --------
// Per step each wave: 2 gload16 for B quarter (Xt pre-swizzled, linear copy)
// + 2 gload16 for its A rows (swizzle via per-lane global addr), then counted
// vmcnt(4) (next tile's 4 loads STAY IN FLIGHT), barrier, 10 ds_read_b128
// (conflict-free by the XOR swizzle) + 8 MFMA, barrier.  No VGPR staging.
// Output in MFMA-B-fragment layout: idx=(((b*196+n/16)*56+c/8)*16+n%16)*8+c%8
template<int NSLAB>
__device__ __forceinline__ void feat_body(
    const __bf16* __restrict__ XtP,    // Xt + pair*NSLAB*4096
    const __bf16* __restrict__ Wrow,   // W + m0*KTOT
    __bf16* __restrict__ y1, int c_base, int b, int n0,
    __bf16 (*Al)[4096], __bf16 (*Bl)[4096])
{
  constexpr int KTOT = NSLAB*64;
  const int lane = threadIdx.x & 63;
  const int wm   = threadIdx.x >> 6;   // 0..3
  const int l15  = lane & 15;
  const int l4   = lane >> 4;
  const int rA   = wm*16 + (lane >> 3);        // A staging row (lanes 0..63 -> 8 rows)
  const int qA   = lane & 7;
  const int swzA = (qA ^ (rA & 7)) << 3;       // (rA+8)&7 == rA&7, same swizzle

  f32x4 acc[4];
  const f32x4 fz = {0.f,0.f,0.f,0.f};
  #pragma unroll
  for (int ni=0; ni<4; ++ni) acc[ni] = fz;

#define STAGE(bsel, t) { \
    const __bf16* _bs = XtP + (size_t)(t)*4096 + wm*1024 + lane*8; \
    gload16(_bs,        &Bl[bsel][wm*1024]); \
    gload16(_bs + 512,  &Bl[bsel][wm*1024 + 512]); \
    const __bf16* _as = Wrow + (size_t)rA*KTOT + (t)*64 + swzA; \
    gload16(_as,                   &Al[bsel][wm*1024]); \
    gload16(_as + (size_t)8*KTOT,  &Al[bsel][wm*1024 + 512]); \
  }

#define COMPUTE(bsel) { \
    const __bf16* _a  = &Al[bsel][wm*1024 + l15*64]; \
    const __bf16* _bb = &Bl[bsel][l15*64]; \
    const int _f = l15 & 7; \
    _Pragma("unroll") \
    for (int kk=0; kk<2; ++kk){ \
      bf16x8 av = *(const bf16x8*)(_a + (((kk*4 + l4) ^ _f)<<3)); \
      _Pragma("unroll") \
      for (int ni=0; ni<4; ++ni){ \
        bf16x8 bv = *(const bf16x8*)(_bb + ni*1024 + (((kk*4 + l4) ^ _f)<<3)); \
        acc[ni] = __builtin_amdgcn_mfma_f32_16x16x32_bf16(av, bv, acc[ni], 0,0,0); \
      } \
    } \
  }

  STAGE(0, 0);
  for (int s=0; s<NSLAB; ++s){
    const int buf = s & 1;
    if (s+1 < NSLAB){
      STAGE(buf^1, s+1);                       // prefetch stays in flight
      __builtin_amdgcn_sched_barrier(0);
      asm volatile("s_waitcnt vmcnt(4)");      // tile s landed; s+1's 4 pending
    } else {
      asm volatile("s_waitcnt vmcnt(0)");
    }
    __builtin_amdgcn_s_barrier();
    __builtin_amdgcn_sched_barrier(0);         // ds_reads stay below (rule #18)
    COMPUTE(buf);
    __builtin_amdgcn_sched_barrier(0);
    __builtin_amdgcn_s_barrier();              // all reads done before restage
  }
#undef STAGE
#undef COMPUTE

  // ---- epilogue: elu + store to fragment layout ----
  const int c0 = c_base + wm*16 + l4*4;
  const int cb = c0 >> 3;
  const int jj = c0 & 7;
  #pragma unroll
  for (int ni=0; ni<4; ++ni){
    const int n = n0 + ni*16 + l15;
    size_t idx = ((((size_t)b*NB16 + (n>>4))*CB8 + cb)*16 + (n&15))*8 + jj;
    f32x4 a = acc[ni];
    bf16x4 o;
    #pragma unroll
    for (int r=0;r<4;++r) o[r] = (__bf16)elu_f(a[r]);
    *(bf16x4*)(y1 + idx) = o;
  }
}

__global__ __launch_bounds__(256) void gemm_feat_fused(
    const __bf16* __restrict__ xt4, const __bf16* __restrict__ xt5,
    const __bf16* __restrict__ xt6,
    const __bf16* __restrict__ w83b, const __bf16* __restrict__ w84b,
    const __bf16* __restrict__ w85b, __bf16* __restrict__ y1)
{
  __shared__ __bf16 Al[2][4096];       // 16 KB A dbuf (64 rows x 64 k)
  __shared__ __bf16 Bl[2][4096];       // 16 KB B dbuf
  const int gid = blockIdx.x;
  if (gid < 800){
    // conv6: 4 mt-blocks of each pair co-located on one XCD (gids = x mod 8)
    const int q = gid >> 5, r = gid & 31, mt = r >> 3, x = r & 7;
    const int pair = q*8 + x;
    if (pair >= 196) return;
    const int b = pair/49, nt = pair%49;
    feat_body<64>(xt6 + (size_t)pair*64*4096, w85b + (size_t)mt*64*4096,
                  y1, 192 + mt*64, b, nt*64, Al, Bl);
  } else if (gid < 1200){
    // conv5: 2 mt-blocks of each pair co-located
    const int g = gid-800, q = g >> 4, r = g & 15, mt = r >> 3, x = r & 7;
    const int pair = q*8 + x;
    if (pair >= 196) return;
    const int b = pair/49, nt = pair%49;
    feat_body<16>(xt5 + (size_t)pair*16*4096, w84b + (size_t)mt*64*1024,
                  y1, 64 + mt*64, b, nt*64, Al, Bl);
  } else {
    // conv4: no sharing
    const int pair = gid-1200;
    const int b = pair/49, nt = pair%49;
    feat_body<8>(xt4 + (size_t)pair*8*4096, w83b,
                 y1, 0, b, nt*64, Al, Bl);
  }
}

// ---------------- output GEMM: x2[n, o] = elu(w9[448x448] * y1) -------------
// LDS-free, barrier-free: both operands frag-loaded direct (L2/L3-resident).
__global__ __launch_bounds__(256) void gemm_out(
    const __bf16* __restrict__ y1, const __bf16* __restrict__ w9b,
    __bf16* __restrict__ x2)
{
  const int nt = blockIdx.x, mt = blockIdx.y, b = blockIdx.z;
  const int tid = threadIdx.x;
  if (mt == 7){
    // zero the pad columns 448..511 of this n-tile
    const int row = tid >> 2, q = tid & 3;
    __bf16* p = x2 + ((size_t)b*N_IMG + nt*64 + row)*512 + 448 + q*16;
    uint4 z = {0u,0u,0u,0u};
    *(uint4*)p = z;
    *(uint4*)(p+8) = z;
    return;
  }
  const int lane = tid & 63, wid = tid >> 6;
  const int l15 = lane & 15, l4 = lane >> 4;
  const __bf16* Bbase = y1 + ((size_t)b*NB16 + nt*4 + wid)*CB8*128;
  const __bf16* Abase = w9b + (size_t)(mt*64 + l15)*448 + l4*8;
  f32x4 acc[4];
  const f32x4 fz = {0.f,0.f,0.f,0.f};
  #pragma unroll
  for (int mi=0;mi<4;++mi) acc[mi] = fz;

  for (int s=0;s<7;++s){
    #pragma unroll
    for (int kk=0;kk<2;++kk){
      bf16x8 bv = *(const bf16x8*)(Bbase + (s*2+kk)*512 + lane*8);  // linear lane*16B
      #pragma unroll
      for (int mi=0;mi<4;++mi){
        bf16x8 av = *(const bf16x8*)(Abase + (size_t)mi*16*448 + s*64 + kk*32);
        acc[mi] = __builtin_amdgcn_mfma_f32_16x16x32_bf16(av, bv, acc[mi], 0,0,0);
      }
    }
  }
  #pragma unroll
  for (int mi=0;mi<4;++mi){
    const int o = mt*64 + mi*16 + l4*4;
    const int n = nt*64 + wid*16 + l15;
    f32x4 a = acc[mi];
    bf16x4 v;
    #pragma unroll
    for (int r=0;r<4;++r) v[r] = (__bf16)elu_f(a[r]);
    *(bf16x4*)(x2 + ((size_t)b*N_IMG + n)*512 + o) = v;
  }
}

// ---------------- affinity stencil: one wave per (b, p) ---------------------
__global__ __launch_bounds__(256) void affinity_kernel(
    const __bf16* __restrict__ x2, float* __restrict__ out)
{
  const int b = blockIdx.x;                 // b fastest -> each XCD sees one batch
  const int lane = threadIdx.x & 63, wid = threadIdx.x >> 6;
  const int p = blockIdx.y*4 + wid;
  const int from = (p/48)*56 + 4 + (p%48);
  const __bf16* xb = x2 + (size_t)b*N_IMG*512;
  bf16x8 ffv = *(const bf16x8*)(xb + (size_t)from*512 + lane*8);
  float ff[8];
  #pragma unroll
  for (int j=0;j<8;++j) ff[j] = (float)ffv[j];
  for (int d=0; d<NDIR; ++d){
    const int to = from + c_offs[d];
    bf16x8 ftv = *(const bf16x8*)(xb + (size_t)to*512 + lane*8);
    float s = 0.f;
    #pragma unroll
    for (int j=0;j<8;++j) s += fabsf(ff[j] - (float)ftv[j]);
    #pragma unroll
    for (int m=1;m<64;m<<=1) s += __shfl_xor(s, m, 64);
    if (lane == 0) out[((size_t)b*NDIR + d)*P_CNT + p] = expf(-s*(1.f/448.f));
  }
}

extern "C" void kernel_launch(void* const* d_in, const int* in_sizes, int n_in,
                              void* d_out, int out_size, void* d_ws, size_t ws_size,
                              hipStream_t stream)
{
  (void)in_sizes; (void)n_in; (void)out_size; (void)ws_size;
  const float* conv4 = (const float*)d_in[0];
  const float* conv5 = (const float*)d_in[1];
  const float* conv6 = (const float*)d_in[2];
  const float* w83   = (const float*)d_in[3];
  const float* w84   = (const float*)d_in[4];
  const float* w85   = (const float*)d_in[5];
  const float* w9    = (const float*)d_in[6];
  // ind_from / ind_to (d_in[7], d_in[8]) are recomputed on device (hardcoded stencil)
  float* out = (float*)d_out;
  char* ws = (char*)d_ws;
  // workspace layout (168,206,336 bytes)
  __bf16* w83b = (__bf16*)(ws + 0);          //  64x512
  __bf16* w84b = (__bf16*)(ws + 65536);      // 128x1024
  __bf16* w85b = (__bf16*)(ws + 327680);     // 256x4096
  __bf16* w9b  = (__bf16*)(ws + 2424832);    // 448x448
  __bf16* y1   = (__bf16*)(ws + 2826240);    // 4*3136*448, fragment layout
  __bf16* x2   = (__bf16*)(ws + 14065664);   // 4*3136*512 (448 + zero pad)
  __bf16* xt6  = (__bf16*)(ws + 26910720);   // 196 pairs x 64 slabs x 8KB
  __bf16* xt5  = (__bf16*)(ws + 129671168);  // 196 x 16 x 8KB
  __bf16* xt4  = (__bf16*)(ws + 155361280);  // 196 x  8 x 8KB

  cvt_weights<<<1380, 256, 0, stream>>>(w83,w84,w85,w9, w83b,w84b,w85b,w9b);
  // [0,3584)=conv6, [3584,4480)=conv5, [4480,4928)=conv4 (split by half-tile)
  xcvt<<<4928, 256, 0, stream>>>(conv4, conv5, conv6, xt4, xt5, xt6);
  // fused, XCD co-located: [0,800)=conv6, [800,1200)=conv5, [1200,1396)=conv4
  gemm_feat_fused<<<1396, 256, 0, stream>>>(xt4, xt5, xt6, w83b, w84b, w85b, y1);
  gemm_out<<<dim3(49,8,4), 256, 0, stream>>>(y1, w9b, x2);
  affinity_kernel<<<dim3(4,624), 256, 0, stream>>>(x2, out);
}